// Round 13
// baseline (477.128 us; speedup 1.0000x reference)
//
#include <hip/hip_runtime.h>
#include <hip/hip_bf16.h>

// ---------------- problem constants (fixed by reference) ----------------
#define B_    256
#define D_    768
#define NI_   65536
#define NC_   8192
#define TT_   128     // tokens per sample
#define KK_   50      // top-k negatives
#define RATE_ 38
#define NBIN_ 4096

#define TOTF_   ((long)NI_ * D_)      // 49152000 floats in new_mem
#define NWIN_   ((TOTF_ - 3 - 5) / 8) // 6143999 8-float windows starting at 3
#define NWIN8_  (NWIN_ / 8)           // 767999 oct-windows

#define NCPB_   256                   // copy blocks
#define NPB_    256                   // patch blocks
#define NMEMT_  (NI_ / 64)            // 1024 mem GEMM tiles (M=256 x N=64)
#define NCLUT_  (NC_ / 64)            // 128 cluster GEMM tiles

constexpr float INVT_ = 20.0f;   // 1/TEMP
constexpr float MOM_  = 0.2f;

typedef __attribute__((ext_vector_type(8))) short          bf16x8;
typedef __attribute__((ext_vector_type(8))) unsigned short u16x8;
typedef __attribute__((ext_vector_type(4))) float          f32x4;

static __device__ __forceinline__ unsigned short f2bf(float f) {
    unsigned int u = __builtin_bit_cast(unsigned int, f);
    unsigned int r = u + 0x7fffu + ((u >> 16) & 1u);   // RNE
    return (unsigned short)(r >> 16);
}
static __device__ __forceinline__ float bf2f(unsigned short u) {
    return __builtin_bit_cast(float, (unsigned int)u << 16);
}
static __device__ __forceinline__ unsigned int pack2(float x, float y) {
    return (unsigned int)f2bf(x) | ((unsigned int)f2bf(y) << 16);
}
static __device__ __forceinline__ int val2bin(float v) {
    int bin = (int)((v + 1.0f) * (float)(NBIN_ / 2));  // fixed range [-1,1]
    return bin < 0 ? 0 : (bin > NBIN_ - 1 ? NBIN_ - 1 : bin);
}
// async global->LDS: per-lane global src, wave-uniform LDS base + lane*16
static __device__ __forceinline__ void glds16(const void* g, void* l) {
    __builtin_amdgcn_global_load_lds(
        (const __attribute__((address_space(1))) void*)g,
        (__attribute__((address_space(3))) void*)l, 16, 0, 0);
}

// ---------------- 1. normalize inputs; zero ghist ----------------
__global__ __launch_bounds__(256) void k_norm_x(const float* __restrict__ in,
                                                float* __restrict__ xf,
                                                unsigned short* __restrict__ xb,
                                                unsigned int* __restrict__ ghist) {
    int b = blockIdx.x, t = threadIdx.x;
    {
        int base = (b * 256 + t) * 16;
#pragma unroll
        for (int i = 0; i < 16; i++) ghist[base + i] = 0u;
    }
    __shared__ float red[256];
    float v[3]; float ss = 0.f;
#pragma unroll
    for (int i = 0; i < 3; i++) { v[i] = in[b * D_ + t + 256 * i]; ss += v[i] * v[i]; }
    red[t] = ss; __syncthreads();
    for (int s = 128; s > 0; s >>= 1) { if (t < s) red[t] += red[t + s]; __syncthreads(); }
    float rn = 1.0f / sqrtf(red[0]);
#pragma unroll
    for (int i = 0; i < 3; i++) {
        float x = v[i] * rn;
        xf[b * D_ + t + 256 * i] = x;
        xb[b * D_ + t + 256 * i] = f2bf(x);
    }
}

// ---------------- 2. MEGA: copy / patch / GEMM, role-interleaved blocks ----------
// bx < 1536: s6 = bx%6 -> s6==0 copy, s6==3 patch, else mem GEMM tile.
// bx >= 1536: cluster GEMM tile. Interleaving puts BW-roles and compute-roles
// on the SAME CU so copy streams hide the GEMM's staging waits.
//
// GEMM tile: M=256 (full batch) x N=64, BK=32, 4 waves (wave = 64M x 64N,
// acc[4][4]). memf rows staged ONCE (one tile per N-strip). m97 structure:
// glds-stage A (bf16 16KB) + B (raw f32 8KB) -> syncthreads -> swizzled
// ds_read frags (B cvt f32->bf16 in-reg) -> 16 MFMA/wave -> barrier.
// LDS XOR-swizzle (T2, rule 21): glds sources pre-swizzled per-lane
// (col ^= lane-row bits), reads use the same XOR -> B-read 16-way -> 2-way.
__global__ __launch_bounds__(256) void k_mega(const unsigned short* __restrict__ A,
                                              const float* __restrict__ memf,
                                              const float* __restrict__ clusf,
                                              unsigned short* __restrict__ mat,
                                              unsigned short* __restrict__ clog,
                                              float* __restrict__ out_f,
                                              const float* __restrict__ cls,
                                              const float* __restrict__ part,
                                              const float* __restrict__ tok,
                                              float* __restrict__ patchL) {
    __shared__ __align__(16) char SMEM[24576];   // As 16KB | Bs 8KB (others reuse)
    const int tid = threadIdx.x;
    const int bx = blockIdx.x;

    int role, rid;   // 0=copy 1=patch 2=memGEMM 3=cluGEMM
    if (bx < 1536) {
        int s6 = bx % 6, q6 = bx / 6;
        if (s6 == 0)      { role = 0; rid = q6; }
        else if (s6 == 3) { role = 1; rid = q6; }
        else              { role = 2; rid = q6 * 4 + (s6 < 3 ? s6 - 1 : s6 - 2); }
    } else { role = 3; rid = bx - 1536; }

    if (role == 0) {
        // ================= copy role: memf -> out_f =================
        // dst=out+1: windows at i==3 (mod 8 base) give 16B-aligned dst stores.
        // 8 windows/iter: 17 loads in flight (fixes R12's 12-VGPR serialization).
        long k8 = (long)rid * 256 + tid;
        for (; k8 < NWIN8_; k8 += (long)NCPB_ * 256) {
            const long s = k8 * 64;
            f32x4 v[17];
#pragma unroll
            for (int i = 0; i < 17; i++) v[i] = *(const f32x4*)(memf + s + i * 4);
#pragma unroll
            for (int i = 0; i < 16; i++) {
                f32x4 w = {v[i].w, v[i + 1].x, v[i + 1].y, v[i + 1].z};
                __builtin_nontemporal_store(w, (f32x4*)(out_f + s + 3 + i * 4));
            }
        }
        if (rid == 0 && tid == 0) {
            for (int i = 0; i < 3; i++) __builtin_nontemporal_store(memf[i], out_f + i);
            for (long i = NWIN8_ * 64 + 3; i < TOTF_; i++)
                __builtin_nontemporal_store(memf[i], out_f + i);
        }
        return;
    }

    if (role == 1) {
        // ================= patch role =================
        float* s  = (float*)SMEM;          // 768
        float* pp = s + D_;                // 256
        float* mp = pp + 256;              // 128
        int b = rid, t = tid;
        int tt = t & 127, h = t >> 7;      // token, D-half
        for (int i = t; i < D_; i += 256) s[i] = 0.5f * (cls[b * D_ + i] + part[b * D_ + i]);
        __syncthreads();
        const float* tr = tok + ((long)b * TT_ + tt) * D_ + h * 384;
        const float* sh = s + h * 384;
        float acc = 0.f;
#pragma unroll 8
        for (int d = 0; d < 384; d += 4) {
            float4 tv = *(const float4*)(tr + d);
            float4 sv = *(const float4*)(sh + d);
            acc += tv.x * sv.x + tv.y * sv.y + tv.z * sv.z + tv.w * sv.w;
        }
        pp[t] = acc; __syncthreads();
        if (t < TT_) mp[t] = pp[t] + pp[t + 128];
        __syncthreads();
        for (int k = 2; k <= TT_; k <<= 1)
            for (int j = k >> 1; j > 0; j >>= 1) {
                if (t < TT_) {
                    int ixj = t ^ j;
                    if (ixj > t) {
                        float a = mp[t], c = mp[ixj];
                        bool up = ((t & k) == 0);
                        if ((a > c) == up) { mp[t] = c; mp[ixj] = a; }
                    }
                }
                __syncthreads();
            }
        if (t == 0) {
            float m = mp[TT_ - 1];
            float sum = 0.f;
            for (int i = 0; i < RATE_; i++) sum += expf((mp[i] - m) * INVT_);
            patchL[b] = log1pf(sum);
        }
        return;
    }

    // ================= GEMM role =================
    unsigned short* As = (unsigned short*)SMEM;          // [256][32] bf16 (64B rows)
    float*          Bs = (float*)(SMEM + 16384);         // [64][32]  f32  (128B rows)

    const int lane = tid & 63, w = tid >> 6;
    const int rl = lane & 15, kg = lane >> 4;

    const float* Bsrc; unsigned short* C; int N; int n0;
    if (role == 2) { Bsrc = memf;  C = mat;  N = NI_; n0 = rid * 64; }
    else           { Bsrc = clusf; C = clog; N = NC_; n0 = rid * 64; }

    // pre-swizzled glds sources (linear LDS dest + XOR'd global col = rule 21)
    const unsigned short* gA = A + (w * 64 + (lane >> 2)) * D_
                                 + (((lane & 3) ^ ((lane >> 2) & 3)) * 8);
    const float* gB = Bsrc + (long)(n0 + w * 16 + (lane >> 3)) * D_
                           + (((lane & 7) ^ (lane >> 3)) * 4);

    // swizzled read slots (thread-constant)
    const int aslot = (kg ^ (rl & 3)) * 16;            // byte offset within 64B A row
    const int p0s   = ((kg * 2) ^ (rl & 7)) * 16;      // byte offset within 128B B row
    const int p1s   = p0s ^ 16;

    f32x4 acc[4][4] = {};

    for (int k0 = 0; k0 < D_; k0 += 32) {
        // ---- stage: A 4 instr/wave (16KB), B 2 instr/wave (8KB)
#pragma unroll
        for (int ii = 0; ii < 4; ii++)
            glds16(gA + ii * 16 * D_ + k0, (char*)As + w * 4096 + ii * 1024);
#pragma unroll
        for (int ii = 0; ii < 2; ii++)
            glds16(gB + ii * 8 * D_ + k0, (char*)Bs + w * 2048 + ii * 1024);
        __syncthreads();   // drains glds (m97 structure)

        // ---- A fragments (swizzled slots)
        bf16x8 af[4];
#pragma unroll
        for (int i = 0; i < 4; i++)
            af[i] = *(const bf16x8*)((const char*)As + (w * 64 + i * 16 + rl) * 64 + aslot);
        // ---- B fragments: two 16B reads at XOR'd slots, cvt to bf16
        uint4 bw[4];
#pragma unroll
        for (int j = 0; j < 4; j++) {
            const char* rb = (const char*)Bs + (j * 16 + rl) * 128;
            float4 p0 = *(const float4*)(rb + p0s);
            float4 p1 = *(const float4*)(rb + p1s);
            bw[j].x = pack2(p0.x, p0.y); bw[j].y = pack2(p0.z, p0.w);
            bw[j].z = pack2(p1.x, p1.y); bw[j].w = pack2(p1.z, p1.w);
        }
        // ---- 16 MFMA / wave
#pragma unroll
        for (int i = 0; i < 4; i++)
#pragma unroll
            for (int j = 0; j < 4; j++)
                acc[i][j] = __builtin_amdgcn_mfma_f32_16x16x32_bf16(
                    af[i], __builtin_bit_cast(bf16x8, bw[j]), acc[i][j], 0, 0, 0);
        __syncthreads();   // LDS reuse
    }

    // epilogue: store bf16 logits (M rows w*64.., N cols n0..n0+64)
#pragma unroll
    for (int i = 0; i < 4; i++)
#pragma unroll
        for (int j = 0; j < 4; j++) {
            int col = n0 + j * 16 + rl;
#pragma unroll
            for (int r = 0; r < 4; r++) {
                int row = w * 64 + i * 16 + kg * 4 + r;
                C[(long)row * N + col] = f2bf(acc[i][j][r]);
            }
        }
}

// ---------------- 4. cluster loss (bf16 logits) ----------------
__global__ __launch_bounds__(256) void k_cluster(const unsigned short* __restrict__ clog,
                                                 const int* __restrict__ targets,
                                                 float* __restrict__ clusterL) {
    int b = blockIdx.x, t = threadIdx.x;
    __shared__ float red[256];
    const u16x8* row = (const u16x8*)(clog + (long)b * NC_);
    float mx = -1e30f;
#pragma unroll
    for (int i = t; i < NC_ / 8; i += 256) {
        u16x8 v = row[i];
#pragma unroll
        for (int e = 0; e < 8; e++) mx = fmaxf(mx, bf2f(v[e]));
    }
    red[t] = mx; __syncthreads();
    for (int s = 128; s > 0; s >>= 1) { if (t < s) red[t] = fmaxf(red[t], red[t + s]); __syncthreads(); }
    mx = red[0]; __syncthreads();
    float sum = 0.f;
#pragma unroll
    for (int i = t; i < NC_ / 8; i += 256) {
        u16x8 v = row[i];
#pragma unroll
        for (int e = 0; e < 8; e++) sum += expf((bf2f(v[e]) - mx) * INVT_);
    }
    red[t] = sum; __syncthreads();
    for (int s = 128; s > 0; s >>= 1) { if (t < s) red[t] += red[t + s]; __syncthreads(); }
    if (t == 0) {
        float lse = mx * INVT_ + logf(red[0]);
        clusterL[b] = lse - bf2f(clog[(long)b * NC_ + targets[b]]) * INVT_;
    }
}

// ---------------- 5a. anchor histogram ----------------
__global__ __launch_bounds__(256) void k_hist(const unsigned short* __restrict__ mat,
                                              const int* __restrict__ targets,
                                              unsigned int* __restrict__ ghist) {
    int b = blockIdx.y, ch = blockIdx.x, t = threadIdx.x;
    int tgt = targets[b];
    __shared__ unsigned int h[NBIN_];
    for (int i = t; i < NBIN_; i += 256) h[i] = 0;
    __syncthreads();
    const u16x8* row = (const u16x8*)(mat + (long)b * NI_);
#pragma unroll
    for (int j = 0; j < 4; j++) {
        int c8 = ch * 1024 + j * 256 + t;
        u16x8 v = row[c8];
        int i0 = c8 * 8;
#pragma unroll
        for (int e = 0; e < 8; e++)
            if (((i0 + e) & (NC_ - 1)) != tgt)   // mem_labels = arange % NC
                atomicAdd(&h[val2bin(bf2f(v[e]))], 1u);
    }
    __syncthreads();
    unsigned int* gh = ghist + (long)b * NBIN_;
    for (int i = t; i < NBIN_; i += 256) { unsigned int c = h[i]; if (c) atomicAdd(&gh[i], c); }
}

// ---------------- 5b. threshold bin ----------------
__global__ __launch_bounds__(256) void k_scan(const unsigned int* __restrict__ ghist,
                                              int* __restrict__ tbv,
                                              unsigned int* __restrict__ gcnt) {
    int b = blockIdx.x, t = threadIdx.x;
    if (t == 0) gcnt[b] = 0;
    const unsigned int* gh = ghist + (long)b * NBIN_;
    __shared__ unsigned int s[256];
    unsigned int sum = 0;
    for (int i = 0; i < 16; i++) sum += gh[t * 16 + i];
    s[t] = sum; __syncthreads();
    for (int off = 1; off < 256; off <<= 1) {
        unsigned int v = (t + off < 256) ? s[t + off] : 0u;
        __syncthreads();
        s[t] += v; __syncthreads();
    }
    unsigned int nextv = (t < 255) ? s[t + 1] : 0u;
    if (s[t] >= KK_ && nextv < KK_) {
        unsigned int cum = nextv;
        int tb = t * 16;
        for (int bin = t * 16 + 15; bin >= t * 16; bin--) {
            cum += gh[bin];
            if (cum >= KK_) { tb = bin; break; }
        }
        tbv[b] = tb;
    }
}

// ---------------- 5c. collect candidates ----------------
__global__ __launch_bounds__(256) void k_collect(const unsigned short* __restrict__ mat,
                                                 const int* __restrict__ targets,
                                                 const int* __restrict__ tbv,
                                                 unsigned int* __restrict__ gcnt,
                                                 float* __restrict__ cand) {
    int b = blockIdx.y, ch = blockIdx.x, t = threadIdx.x;
    int tgt = targets[b];
    int tb = tbv[b];
    const u16x8* row = (const u16x8*)(mat + (long)b * NI_);
#pragma unroll
    for (int j = 0; j < 4; j++) {
        int c8 = ch * 1024 + j * 256 + t;
        u16x8 v = row[c8];
        int i0 = c8 * 8;
#pragma unroll
        for (int e = 0; e < 8; e++) {
            float f = bf2f(v[e]);
            if (((i0 + e) & (NC_ - 1)) != tgt && val2bin(f) >= tb) {
                unsigned int p = atomicAdd(&gcnt[b], 1u);
                if (p < 256) cand[b * 256 + p] = f;
            }
        }
    }
}

// ---------------- 5d. sort candidates, anchor loss ----------------
__global__ __launch_bounds__(256) void k_final(const unsigned short* __restrict__ mat,
                                               const int* __restrict__ targets,
                                               const unsigned int* __restrict__ gcnt,
                                               const float* __restrict__ cand,
                                               float* __restrict__ anchorL) {
    int b = blockIdx.x, t = threadIdx.x;
    int tgt = targets[b];
    __shared__ float c[256];
    __shared__ float pm[8];
    unsigned int n = gcnt[b]; if (n > 256u) n = 256u;
    c[t] = (t < (int)n) ? cand[b * 256 + t] : -1e30f;
    if (t < 8) pm[t] = bf2f(mat[(long)b * NI_ + tgt + t * NC_]);   // the 8 positives
    __syncthreads();
    for (int k = 2; k <= 256; k <<= 1)
        for (int j = k >> 1; j > 0; j >>= 1) {
            int ixj = t ^ j;
            if (ixj > t) {
                float a = c[t], d = c[ixj];
                bool down = ((t & k) == 0);
                if ((a < d) == down) { c[t] = d; c[ixj] = a; }
            }
            __syncthreads();
        }
    if (t == 0) {
        float posmin = pm[0];
        for (int i = 1; i < 8; i++) posmin = fminf(posmin, pm[i]);
        float m = fmaxf(posmin, c[0]);
        float sum = expf((posmin - m) * INVT_);
        for (int i = 0; i < KK_; i++) sum += expf((c[i] - m) * INVT_);
        anchorL[b] = m * INVT_ + logf(sum) - posmin * INVT_;
    }
}

// ---------------- 6. momentum scatter-update ----------------
__global__ __launch_bounds__(256) void k_update(const float* __restrict__ mem,
                                                const float* __restrict__ xf,
                                                const int* __restrict__ indexes,
                                                float* __restrict__ out_mem) {
    int b = blockIdx.x, t = threadIdx.x;
    int idx = indexes[b];
    __shared__ float red[256];
    float u[3]; float ss = 0.f;
#pragma unroll
    for (int i = 0; i < 3; i++) {
        int d = t + 256 * i;
        u[i] = MOM_ * mem[(long)idx * D_ + d] + (1.0f - MOM_) * xf[b * D_ + d];
        ss += u[i] * u[i];
    }
    red[t] = ss; __syncthreads();
    for (int s = 128; s > 0; s >>= 1) { if (t < s) red[t] += red[t + s]; __syncthreads(); }
    float rn = 1.0f / sqrtf(red[0]);
#pragma unroll
    for (int i = 0; i < 3; i++) {
        int d = t + 256 * i;
        out_mem[(long)idx * D_ + d] = u[i] * rn;
    }
}

// ---------------- 7. final loss ----------------
__global__ __launch_bounds__(256) void k_loss(const float* __restrict__ pL,
                                              const float* __restrict__ aL,
                                              const float* __restrict__ cL,
                                              float* __restrict__ out) {
    int t = threadIdx.x;
    __shared__ float red[256];
    red[t] = pL[t] + aL[t] + cL[t];
    __syncthreads();
    for (int s = 128; s > 0; s >>= 1) { if (t < s) red[t] += red[t + s]; __syncthreads(); }
    if (t == 0) out[0] = red[0] / (float)B_;
}

extern "C" void kernel_launch(void* const* d_in, const int* in_sizes, int n_in,
                              void* d_out, int out_size, void* d_ws, size_t ws_size,
                              hipStream_t stream) {
    const float* inputs   = (const float*)d_in[0];
    const float* cls_tok  = (const float*)d_in[1];
    const float* part_tok = (const float*)d_in[2];
    const float* tokens   = (const float*)d_in[3];
    const float* mem_f    = (const float*)d_in[4];
    const float* clus_f   = (const float*)d_in[5];
    const int*   targets  = (const int*)d_in[6];
    const int*   indexes  = (const int*)d_in[7];

    // workspace layout:
    //   xf    @ 0         (786432)
    //   xb    @ 786432    (393216)  -- dead after GEMM; cand/gcnt/tbv alias here
    //   mat   @ 1179648   (bf16, 33554432)
    //   clog  @ 34734080  (bf16, 4194304)
    //   ghist @ 38928384  (4194304)  -- zeroed in k_norm_x
    //   losses @ 43122688
    char* ws = (char*)d_ws;
    float*          xf      = (float*)(ws);
    unsigned short* xb      = (unsigned short*)(ws + 786432);
    float*          cand    = (float*)(ws + 786432);          // alias xb (post-GEMM)
    unsigned int*   gcnt    = (unsigned int*)(ws + 1048576);  // alias xb
    int*            tbv     = (int*)(ws + 1049600);           // alias xb
    unsigned short* mat     = (unsigned short*)(ws + 1179648);
    unsigned short* clog    = (unsigned short*)(ws + 34734080);
    unsigned int*   ghist   = (unsigned int*)(ws + 38928384);
    float*          patchL  = (float*)(ws + 43122688);
    float*          anchorL = (float*)(ws + 43123712);
    float*          clusterL= (float*)(ws + 43124736);

    float* out   = (float*)d_out;
    float* out_f = out + 1;   // new_mem flat

    k_norm_x<<<B_, 256, 0, stream>>>(inputs, xf, xb, ghist);

    // mega: interleaved copy/patch/memGEMM blocks [0,1536) + cluster [1536,1664)
    k_mega<<<1536 + NCLUT_, 256, 0, stream>>>(
        xb, mem_f, clus_f, mat, clog, out_f, cls_tok, part_tok, tokens, patchL);

    k_cluster<<<B_, 256, 0, stream>>>(clog, targets, clusterL);

    k_hist<<<dim3(8, B_), 256, 0, stream>>>(mat, targets, ghist);
    k_scan<<<B_, 256, 0, stream>>>(ghist, tbv, gcnt);
    k_collect<<<dim3(8, B_), 256, 0, stream>>>(mat, targets, tbv, gcnt, cand);
    k_final<<<B_, 256, 0, stream>>>(mat, targets, gcnt, cand, anchorL);

    k_update<<<B_, 256, 0, stream>>>(mem_f, xf, indexes, out_f);

    k_loss<<<1, 256, 0, stream>>>(patchL, anchorL, clusterL, out);
}

// Round 14
// 227.624 us; speedup vs baseline: 2.0961x; 2.0961x over previous
//
#include <hip/hip_runtime.h>
#include <hip/hip_bf16.h>

// ---------------- problem constants (fixed by reference) ----------------
#define B_    256
#define D_    768
#define NI_   65536
#define NC_   8192
#define TT_   128     // tokens per sample
#define KK_   50      // top-k negatives
#define RATE_ 38
#define NBIN_ 4096

#define TOTF_   ((long)NI_ * D_)      // 49152000 floats in new_mem
#define MMAX_   ((TOTF_ - 3) / 4)     // 12287999: last aligned dst-float4 index

#define PBLK_   256                   // patch blocks in gemm dispatch
#define NMEMT_  (NI_ / 64)            // 1024 mem GEMM tiles (M=256 x N=64)
#define NCLUT_  (NC_ / 64)            // 128 cluster GEMM tiles

constexpr float INVT_ = 20.0f;   // 1/TEMP
constexpr float MOM_  = 0.2f;

typedef __attribute__((ext_vector_type(8))) short          bf16x8;
typedef __attribute__((ext_vector_type(8))) unsigned short u16x8;
typedef __attribute__((ext_vector_type(4))) float          f32x4;

static __device__ __forceinline__ unsigned short f2bf(float f) {
    unsigned int u = __builtin_bit_cast(unsigned int, f);
    unsigned int r = u + 0x7fffu + ((u >> 16) & 1u);   // RNE
    return (unsigned short)(r >> 16);
}
static __device__ __forceinline__ float bf2f(unsigned short u) {
    return __builtin_bit_cast(float, (unsigned int)u << 16);
}
static __device__ __forceinline__ unsigned int pack2(float x, float y) {
    return (unsigned int)f2bf(x) | ((unsigned int)f2bf(y) << 16);
}
static __device__ __forceinline__ int val2bin(float v) {
    int bin = (int)((v + 1.0f) * (float)(NBIN_ / 2));  // fixed range [-1,1]
    return bin < 0 ? 0 : (bin > NBIN_ - 1 ? NBIN_ - 1 : bin);
}
// async global->LDS: per-lane global src, wave-uniform LDS base + lane*16
static __device__ __forceinline__ void glds16(const void* g, void* l) {
    __builtin_amdgcn_global_load_lds(
        (const __attribute__((address_space(1))) void*)g,
        (__attribute__((address_space(3))) void*)l, 16, 0, 0);
}

// ---------------- 1. normalize inputs; zero ghist ----------------
__global__ __launch_bounds__(256) void k_norm_x(const float* __restrict__ in,
                                                float* __restrict__ xf,
                                                unsigned short* __restrict__ xb,
                                                unsigned int* __restrict__ ghist) {
    int b = blockIdx.x, t = threadIdx.x;
    {
        int base = (b * 256 + t) * 16;
#pragma unroll
        for (int i = 0; i < 16; i++) ghist[base + i] = 0u;
    }
    __shared__ float red[256];
    float v[3]; float ss = 0.f;
#pragma unroll
    for (int i = 0; i < 3; i++) { v[i] = in[b * D_ + t + 256 * i]; ss += v[i] * v[i]; }
    red[t] = ss; __syncthreads();
    for (int s = 128; s > 0; s >>= 1) { if (t < s) red[t] += red[t + s]; __syncthreads(); }
    float rn = 1.0f / sqrtf(red[0]);
#pragma unroll
    for (int i = 0; i < 3; i++) {
        float x = v[i] * rn;
        xf[b * D_ + t + 256 * i] = x;
        xb[b * D_ + t + 256 * i] = f2bf(x);
    }
}

// ---------------- 2. streaming copy: ALIGNED both sides via shfl shift ----------
// dst float4 index m (on out base): out4[m] = {src[4m-1], src[4m], src[4m+1],
// src[4m+2]}. Lane i loads ALIGNED a = src4[m]; prev element comes from lane
// i-1 via shfl_up (lane 0 loads the scalar). Both load & store fully aligned
// (m13 pattern + 1 shfl). NT stores keep memf L3-resident for the GEMM.
__global__ __launch_bounds__(256) void k_stream(const float* __restrict__ src,
                                                float* __restrict__ out /* = d_out */) {
    const long gid = (long)blockIdx.x * 256 + threadIdx.x;
    const long stride = (long)gridDim.x * 256;
    const int lane = threadIdx.x & 63;
    for (long m = 1 + gid; m - lane <= MMAX_; m += stride) {   // wave-uniform continue
        bool ok = (m <= MMAX_);
        f32x4 a = {0.f, 0.f, 0.f, 0.f};
        if (ok) a = *(const f32x4*)(src + 4 * m);
        float p = __shfl_up(a.w, 1);
        if (lane == 0 && ok) p = src[4 * m - 1];
        if (ok) {
            f32x4 w = {p, a.x, a.y, a.z};
            __builtin_nontemporal_store(w, (f32x4*)(out) + m);
        }
    }
    if (gid == 0) {   // head src[0..3) -> out[1..4); tail src[TOTF_-1]
        __builtin_nontemporal_store(src[0], out + 1);
        __builtin_nontemporal_store(src[1], out + 2);
        __builtin_nontemporal_store(src[2], out + 3);
        __builtin_nontemporal_store(src[TOTF_ - 1], out + TOTF_);
    }
}

// ---------------- 3. GEMM dispatch (m97 structure, swizzled LDS) + patch ---------
// blocks [0,256): patch; [256,1280): mem tiles; [1280,1408): cluster tiles.
// Tile M=256 (full batch) x N=64, BK=32, 4 waves (wave = 64M x 64N, acc[4][4]).
// memf staged ONCE. glds-stage A (bf16 16KB) + B (raw f32 8KB) -> syncthreads
// -> swizzled ds_read frags (B cvt f32->bf16 in-reg) -> 16 MFMA/wave -> barrier.
// XOR swizzle (rule 21, verified R13): pre-swizzled glds SOURCE cols + same-XOR
// read slots. B: key=row&7 -> 16-way->2-way (free). A: key=(row>>1)&3 ->
// quad=(4(rl&1)+kg^((rl>>1)&3)) mod 8 covers all 8 -> 2-way (free).
__global__ __launch_bounds__(256) void k_gemm(const unsigned short* __restrict__ A,
                                              const float* __restrict__ memf,
                                              const float* __restrict__ clusf,
                                              unsigned short* __restrict__ mat,
                                              unsigned short* __restrict__ clog,
                                              const float* __restrict__ cls,
                                              const float* __restrict__ part,
                                              const float* __restrict__ tok,
                                              float* __restrict__ patchL) {
    __shared__ __align__(16) char SMEM[24576];   // As 16KB | Bs 8KB (patch reuses)
    const int tid = threadIdx.x;
    const int bx = blockIdx.x;

    if (bx < PBLK_) {
        // ================= patch role =================
        float* s  = (float*)SMEM;          // 768
        float* pp = s + D_;                // 256
        float* mp = pp + 256;              // 128
        int b = bx, t = tid;
        int tt = t & 127, h = t >> 7;      // token, D-half
        for (int i = t; i < D_; i += 256) s[i] = 0.5f * (cls[b * D_ + i] + part[b * D_ + i]);
        __syncthreads();
        const float* tr = tok + ((long)b * TT_ + tt) * D_ + h * 384;
        const float* sh = s + h * 384;
        float acc = 0.f;
#pragma unroll 8
        for (int d = 0; d < 384; d += 4) {
            float4 tv = *(const float4*)(tr + d);
            float4 sv = *(const float4*)(sh + d);
            acc += tv.x * sv.x + tv.y * sv.y + tv.z * sv.z + tv.w * sv.w;
        }
        pp[t] = acc; __syncthreads();
        if (t < TT_) mp[t] = pp[t] + pp[t + 128];
        __syncthreads();
        for (int k = 2; k <= TT_; k <<= 1)
            for (int j = k >> 1; j > 0; j >>= 1) {
                if (t < TT_) {
                    int ixj = t ^ j;
                    if (ixj > t) {
                        float a = mp[t], c = mp[ixj];
                        bool up = ((t & k) == 0);
                        if ((a > c) == up) { mp[t] = c; mp[ixj] = a; }
                    }
                }
                __syncthreads();
            }
        if (t == 0) {
            float m = mp[TT_ - 1];
            float sum = 0.f;
            for (int i = 0; i < RATE_; i++) sum += expf((mp[i] - m) * INVT_);
            patchL[b] = log1pf(sum);
        }
        return;
    }

    // ================= GEMM role =================
    unsigned short* As = (unsigned short*)SMEM;          // [256][32] bf16 (64B rows)
    float*          Bs = (float*)(SMEM + 16384);         // [64][32]  f32  (128B rows)

    const int lane = tid & 63, w = tid >> 6;
    const int rl = lane & 15, kg = lane >> 4;

    const float* Bsrc; unsigned short* C; int N; int n0;
    if (bx < PBLK_ + NMEMT_) { Bsrc = memf;  C = mat;  N = NI_; n0 = (bx - PBLK_) * 64; }
    else                     { Bsrc = clusf; C = clog; N = NC_; n0 = (bx - PBLK_ - NMEMT_) * 64; }

    // pre-swizzled glds sources (linear LDS dest + XOR'd global col)
    // A: stage row (within instr) = lane>>2, group = lane&3, key = (lane>>3)&3
    const unsigned short* gA = A + (w * 64 + (lane >> 2)) * D_
                                 + (((lane & 3) ^ ((lane >> 3) & 3)) * 8);
    // B: stage row = lane>>3, group = lane&7, key = (lane>>3)&7
    const float* gB = Bsrc + (long)(n0 + w * 16 + (lane >> 3)) * D_
                           + (((lane & 7) ^ (lane >> 3)) * 4);

    // swizzled read slots (thread-constant byte offsets)
    const int aslot = (kg ^ ((rl >> 1) & 3)) * 16;     // within 64B A row
    const int p0s   = ((kg * 2) ^ (rl & 7)) * 16;      // within 128B B row
    const int p1s   = p0s ^ 16;

    f32x4 acc[4][4] = {};

    for (int k0 = 0; k0 < D_; k0 += 32) {
        // ---- stage: A 4 instr/wave (16KB), B 2 instr/wave (8KB)
#pragma unroll
        for (int ii = 0; ii < 4; ii++)
            glds16(gA + ii * 16 * D_ + k0, (char*)As + w * 4096 + ii * 1024);
#pragma unroll
        for (int ii = 0; ii < 2; ii++)
            glds16(gB + ii * 8 * D_ + k0, (char*)Bs + w * 2048 + ii * 1024);
        __syncthreads();   // drains glds (m97 structure)

        // ---- A fragments (swizzled slots)
        bf16x8 af[4];
#pragma unroll
        for (int i = 0; i < 4; i++)
            af[i] = *(const bf16x8*)((const char*)As + (w * 64 + i * 16 + rl) * 64 + aslot);
        // ---- B fragments: two 16B reads at XOR'd slots, cvt to bf16
        uint4 bw[4];
#pragma unroll
        for (int j = 0; j < 4; j++) {
            const char* rb = (const char*)Bs + (j * 16 + rl) * 128;
            float4 p0 = *(const float4*)(rb + p0s);
            float4 p1 = *(const float4*)(rb + p1s);
            bw[j].x = pack2(p0.x, p0.y); bw[j].y = pack2(p0.z, p0.w);
            bw[j].z = pack2(p1.x, p1.y); bw[j].w = pack2(p1.z, p1.w);
        }
        // ---- 16 MFMA / wave
#pragma unroll
        for (int i = 0; i < 4; i++)
#pragma unroll
            for (int j = 0; j < 4; j++)
                acc[i][j] = __builtin_amdgcn_mfma_f32_16x16x32_bf16(
                    af[i], __builtin_bit_cast(bf16x8, bw[j]), acc[i][j], 0, 0, 0);
        __syncthreads();   // LDS reuse
    }

    // epilogue: store bf16 logits (M rows w*64.., N cols n0..n0+64)
#pragma unroll
    for (int i = 0; i < 4; i++)
#pragma unroll
        for (int j = 0; j < 4; j++) {
            int col = n0 + j * 16 + rl;
#pragma unroll
            for (int r = 0; r < 4; r++) {
                int row = w * 64 + i * 16 + kg * 4 + r;
                C[(long)row * N + col] = f2bf(acc[i][j][r]);
            }
        }
}

// ---------------- 4. cluster loss (bf16 logits) ----------------
__global__ __launch_bounds__(256) void k_cluster(const unsigned short* __restrict__ clog,
                                                 const int* __restrict__ targets,
                                                 float* __restrict__ clusterL) {
    int b = blockIdx.x, t = threadIdx.x;
    __shared__ float red[256];
    const u16x8* row = (const u16x8*)(clog + (long)b * NC_);
    float mx = -1e30f;
#pragma unroll
    for (int i = t; i < NC_ / 8; i += 256) {
        u16x8 v = row[i];
#pragma unroll
        for (int e = 0; e < 8; e++) mx = fmaxf(mx, bf2f(v[e]));
    }
    red[t] = mx; __syncthreads();
    for (int s = 128; s > 0; s >>= 1) { if (t < s) red[t] = fmaxf(red[t], red[t + s]); __syncthreads(); }
    mx = red[0]; __syncthreads();
    float sum = 0.f;
#pragma unroll
    for (int i = t; i < NC_ / 8; i += 256) {
        u16x8 v = row[i];
#pragma unroll
        for (int e = 0; e < 8; e++) sum += expf((bf2f(v[e]) - mx) * INVT_);
    }
    red[t] = sum; __syncthreads();
    for (int s = 128; s > 0; s >>= 1) { if (t < s) red[t] += red[t + s]; __syncthreads(); }
    if (t == 0) {
        float lse = mx * INVT_ + logf(red[0]);
        clusterL[b] = lse - bf2f(clog[(long)b * NC_ + targets[b]]) * INVT_;
    }
}

// ---------------- 5a. anchor histogram ----------------
__global__ __launch_bounds__(256) void k_hist(const unsigned short* __restrict__ mat,
                                              const int* __restrict__ targets,
                                              unsigned int* __restrict__ ghist) {
    int b = blockIdx.y, ch = blockIdx.x, t = threadIdx.x;
    int tgt = targets[b];
    __shared__ unsigned int h[NBIN_];
    for (int i = t; i < NBIN_; i += 256) h[i] = 0;
    __syncthreads();
    const u16x8* row = (const u16x8*)(mat + (long)b * NI_);
#pragma unroll
    for (int j = 0; j < 4; j++) {
        int c8 = ch * 1024 + j * 256 + t;
        u16x8 v = row[c8];
        int i0 = c8 * 8;
#pragma unroll
        for (int e = 0; e < 8; e++)
            if (((i0 + e) & (NC_ - 1)) != tgt)   // mem_labels = arange % NC
                atomicAdd(&h[val2bin(bf2f(v[e]))], 1u);
    }
    __syncthreads();
    unsigned int* gh = ghist + (long)b * NBIN_;
    for (int i = t; i < NBIN_; i += 256) { unsigned int c = h[i]; if (c) atomicAdd(&gh[i], c); }
}

// ---------------- 5b. threshold bin ----------------
__global__ __launch_bounds__(256) void k_scan(const unsigned int* __restrict__ ghist,
                                              int* __restrict__ tbv,
                                              unsigned int* __restrict__ gcnt) {
    int b = blockIdx.x, t = threadIdx.x;
    if (t == 0) gcnt[b] = 0;
    const unsigned int* gh = ghist + (long)b * NBIN_;
    __shared__ unsigned int s[256];
    unsigned int sum = 0;
    for (int i = 0; i < 16; i++) sum += gh[t * 16 + i];
    s[t] = sum; __syncthreads();
    for (int off = 1; off < 256; off <<= 1) {
        unsigned int v = (t + off < 256) ? s[t + off] : 0u;
        __syncthreads();
        s[t] += v; __syncthreads();
    }
    unsigned int nextv = (t < 255) ? s[t + 1] : 0u;
    if (s[t] >= KK_ && nextv < KK_) {
        unsigned int cum = nextv;
        int tb = t * 16;
        for (int bin = t * 16 + 15; bin >= t * 16; bin--) {
            cum += gh[bin];
            if (cum >= KK_) { tb = bin; break; }
        }
        tbv[b] = tb;
    }
}

// ---------------- 5c. collect candidates ----------------
__global__ __launch_bounds__(256) void k_collect(const unsigned short* __restrict__ mat,
                                                 const int* __restrict__ targets,
                                                 const int* __restrict__ tbv,
                                                 unsigned int* __restrict__ gcnt,
                                                 float* __restrict__ cand) {
    int b = blockIdx.y, ch = blockIdx.x, t = threadIdx.x;
    int tgt = targets[b];
    int tb = tbv[b];
    const u16x8* row = (const u16x8*)(mat + (long)b * NI_);
#pragma unroll
    for (int j = 0; j < 4; j++) {
        int c8 = ch * 1024 + j * 256 + t;
        u16x8 v = row[c8];
        int i0 = c8 * 8;
#pragma unroll
        for (int e = 0; e < 8; e++) {
            float f = bf2f(v[e]);
            if (((i0 + e) & (NC_ - 1)) != tgt && val2bin(f) >= tb) {
                unsigned int p = atomicAdd(&gcnt[b], 1u);
                if (p < 256) cand[b * 256 + p] = f;
            }
        }
    }
}

// ---------------- 5d. sort candidates, anchor loss ----------------
__global__ __launch_bounds__(256) void k_final(const unsigned short* __restrict__ mat,
                                               const int* __restrict__ targets,
                                               const unsigned int* __restrict__ gcnt,
                                               const float* __restrict__ cand,
                                               float* __restrict__ anchorL) {
    int b = blockIdx.x, t = threadIdx.x;
    int tgt = targets[b];
    __shared__ float c[256];
    __shared__ float pm[8];
    unsigned int n = gcnt[b]; if (n > 256u) n = 256u;
    c[t] = (t < (int)n) ? cand[b * 256 + t] : -1e30f;
    if (t < 8) pm[t] = bf2f(mat[(long)b * NI_ + tgt + t * NC_]);   // the 8 positives
    __syncthreads();
    for (int k = 2; k <= 256; k <<= 1)
        for (int j = k >> 1; j > 0; j >>= 1) {
            int ixj = t ^ j;
            if (ixj > t) {
                float a = c[t], d = c[ixj];
                bool down = ((t & k) == 0);
                if ((a < d) == down) { c[t] = d; c[ixj] = a; }
            }
            __syncthreads();
        }
    if (t == 0) {
        float posmin = pm[0];
        for (int i = 1; i < 8; i++) posmin = fminf(posmin, pm[i]);
        float m = fmaxf(posmin, c[0]);
        float sum = expf((posmin - m) * INVT_);
        for (int i = 0; i < KK_; i++) sum += expf((c[i] - m) * INVT_);
        anchorL[b] = m * INVT_ + logf(sum) - posmin * INVT_;
    }
}

// ---------------- 6. momentum scatter-update ----------------
__global__ __launch_bounds__(256) void k_update(const float* __restrict__ mem,
                                                const float* __restrict__ xf,
                                                const int* __restrict__ indexes,
                                                float* __restrict__ out_mem) {
    int b = blockIdx.x, t = threadIdx.x;
    int idx = indexes[b];
    __shared__ float red[256];
    float u[3]; float ss = 0.f;
#pragma unroll
    for (int i = 0; i < 3; i++) {
        int d = t + 256 * i;
        u[i] = MOM_ * mem[(long)idx * D_ + d] + (1.0f - MOM_) * xf[b * D_ + d];
        ss += u[i] * u[i];
    }
    red[t] = ss; __syncthreads();
    for (int s = 128; s > 0; s >>= 1) { if (t < s) red[t] += red[t + s]; __syncthreads(); }
    float rn = 1.0f / sqrtf(red[0]);
#pragma unroll
    for (int i = 0; i < 3; i++) {
        int d = t + 256 * i;
        out_mem[(long)idx * D_ + d] = u[i] * rn;
    }
}

// ---------------- 7. final loss ----------------
__global__ __launch_bounds__(256) void k_loss(const float* __restrict__ pL,
                                              const float* __restrict__ aL,
                                              const float* __restrict__ cL,
                                              float* __restrict__ out) {
    int t = threadIdx.x;
    __shared__ float red[256];
    red[t] = pL[t] + aL[t] + cL[t];
    __syncthreads();
    for (int s = 128; s > 0; s >>= 1) { if (t < s) red[t] += red[t + s]; __syncthreads(); }
    if (t == 0) out[0] = red[0] / (float)B_;
}

extern "C" void kernel_launch(void* const* d_in, const int* in_sizes, int n_in,
                              void* d_out, int out_size, void* d_ws, size_t ws_size,
                              hipStream_t stream) {
    const float* inputs   = (const float*)d_in[0];
    const float* cls_tok  = (const float*)d_in[1];
    const float* part_tok = (const float*)d_in[2];
    const float* tokens   = (const float*)d_in[3];
    const float* mem_f    = (const float*)d_in[4];
    const float* clus_f   = (const float*)d_in[5];
    const int*   targets  = (const int*)d_in[6];
    const int*   indexes  = (const int*)d_in[7];

    // workspace layout:
    //   xf    @ 0         (786432)
    //   xb    @ 786432    (393216)  -- dead after GEMM; cand/gcnt/tbv alias here
    //   mat   @ 1179648   (bf16, 33554432)
    //   clog  @ 34734080  (bf16, 4194304)
    //   ghist @ 38928384  (4194304)  -- zeroed in k_norm_x
    //   losses @ 43122688
    char* ws = (char*)d_ws;
    float*          xf      = (float*)(ws);
    unsigned short* xb      = (unsigned short*)(ws + 786432);
    float*          cand    = (float*)(ws + 786432);          // alias xb (post-GEMM)
    unsigned int*   gcnt    = (unsigned int*)(ws + 1048576);  // alias xb
    int*            tbv     = (int*)(ws + 1049600);           // alias xb
    unsigned short* mat     = (unsigned short*)(ws + 1179648);
    unsigned short* clog    = (unsigned short*)(ws + 34734080);
    unsigned int*   ghist   = (unsigned int*)(ws + 38928384);
    float*          patchL  = (float*)(ws + 43122688);
    float*          anchorL = (float*)(ws + 43123712);
    float*          clusterL= (float*)(ws + 43124736);

    float* out   = (float*)d_out;
    float* out_f = out + 1;   // new_mem flat

    k_norm_x<<<B_, 256, 0, stream>>>(inputs, xf, xb, ghist);

    // copy (aligned-both-sides shfl pattern; warms L3 with memf for the GEMM)
    k_stream<<<2048, 256, 0, stream>>>(mem_f, out);

    // gemm dispatch: [0,256) patch; [256,1280) mem tiles; [1280,1408) cluster tiles
    k_gemm<<<PBLK_ + NMEMT_ + NCLUT_, 256, 0, stream>>>(
        xb, mem_f, clus_f, mat, clog, cls_tok, part_tok, tokens, patchL);

    k_cluster<<<B_, 256, 0, stream>>>(clog, targets, clusterL);

    k_hist<<<dim3(8, B_), 256, 0, stream>>>(mat, targets, ghist);
    k_scan<<<B_, 256, 0, stream>>>(ghist, tbv, gcnt);
    k_collect<<<dim3(8, B_), 256, 0, stream>>>(mat, targets, tbv, gcnt, cand);
    k_final<<<B_, 256, 0, stream>>>(mat, targets, gcnt, cand, anchorL);

    k_update<<<B_, 256, 0, stream>>>(mem_f, xf, indexes, out_f);

    k_loss<<<1, 256, 0, stream>>>(patchL, anchorL, clusterL, out);
}